// Round 17
// baseline (114.305 us; speedup 1.0000x reference)
//
#include <hip/hip_runtime.h>
#include <hip/hip_bf16.h>
#include <math.h>

typedef __bf16 bf16;
typedef bf16 bf16x4 __attribute__((ext_vector_type(4)));
typedef bf16 bf16x8 __attribute__((ext_vector_type(8)));
typedef float f32x4 __attribute__((ext_vector_type(4)));
typedef float f32x16 __attribute__((ext_vector_type(16)));
typedef unsigned int uint;

#define EMB 1024
#define SEQ 2048
#define BATCH 2
#define NH 16
#define HD 64

#define SCALE2 0.18033688011112042f   // (1/8) * log2(e), folded into Q

// async global->LDS, 16B per lane (dest = wave-uniform base + lane*16)
__device__ __forceinline__ void glds16(const void* g, void* l) {
  __builtin_amdgcn_global_load_lds(
      (__attribute__((address_space(1))) void*)g,
      (__attribute__((address_space(3))) void*)l, 16, 0, 0);
}

// pack two f32 -> packed bf16 pair (lo=src0, hi=src1)
__device__ __forceinline__ uint cvtpk(float lo, float hi) {
  uint r;
  asm("v_cvt_pk_bf16_f32 %0, %1, %2" : "=v"(r) : "v"(lo), "v"(hi));
  return r;
}
// v_permlane32_swap_b32: a <- [a.row0, b.row0], b <- [a.row1, b.row1]
__device__ __forceinline__ void plswap(uint& a, uint& b) {
  asm("v_permlane32_swap_b32 %0, %1" : "+v"(a), "+v"(b));
}

// ---------------- fused prep: x cvt + W_qkv^T + W_out^T in ONE dispatch ----------------
__global__ __launch_bounds__(256) void prep_fused(
    const float* __restrict__ x, bf16* __restrict__ xb,
    const float* __restrict__ Wqkv, bf16* __restrict__ wqkvt,
    const float* __restrict__ Wout, bf16* __restrict__ woutt) {
  __shared__ float tile[32][33];
  const int blk = blockIdx.x;
  const int t = threadIdx.x;

  if (blk < 4096) {
    const int i = (blk * 256 + t) * 4;
    float4 v = *reinterpret_cast<const float4*>(x + i);
    xb[i + 0] = (bf16)v.x;
    xb[i + 1] = (bf16)v.y;
    xb[i + 2] = (bf16)v.z;
    xb[i + 3] = (bf16)v.w;
    return;
  }

  const float* in;
  bf16* out;
  int R, C, bx, by;
  if (blk < 7168) {
    const int bb = blk - 4096;           // grid (96, 32)
    in = Wqkv; out = wqkvt; R = 1024; C = 3072;
    bx = bb % 96; by = bb / 96;
  } else {
    const int bb = blk - 7168;           // grid (32, 32)
    in = Wout; out = woutt; R = 1024; C = 1024;
    bx = bb & 31; by = bb >> 5;
  }
  const int c0 = bx * 32, r0 = by * 32;
  const int tx = t & 31, ty = t >> 5;    // 32 x 8
#pragma unroll
  for (int i = 0; i < 32; i += 8)
    tile[ty + i][tx] = in[(size_t)(r0 + ty + i) * C + c0 + tx];
  __syncthreads();
#pragma unroll
  for (int i = 0; i < 32; i += 8)
    out[(size_t)(c0 + ty + i) * R + r0 + tx] = (bf16)tile[tx][ty + i];
}

// ---------------- QKV GEMM: 256x128 tile, 8 waves, BK=32, 3-buffer depth-2 pipeline --
// Stage tile kt+2 at tile kt's top; counted vmcnt(6) leaves tiles kt+1,kt+2 in
// flight across BOTH barriers (true T4 slack: tile kt's loads were issued two
// K-steps earlier).  LDS ring of 3 buffers (72 KB -> 2 blocks/CU).
#define QBM 256
#define QBN 128
#define QBK 32

__global__ __launch_bounds__(512) void gemm_qkv(
    const bf16* __restrict__ A, const bf16* __restrict__ Bt,
    const float* __restrict__ bias, int M, int N, int K,
    bf16* __restrict__ outQ, bf16* __restrict__ outK, bf16* __restrict__ outVt) {
  __shared__ bf16 Alds[3][QBM * QBK];   // 3 x 16 KB
  __shared__ bf16 Blds[3][QBN * QBK];   // 3 x  8 KB

  const int t = threadIdx.x;
  const int lane = t & 63;
  const int w = t >> 6;
  const int wr = w >> 1, wc = w & 1;
  const int lg = lane >> 4, lr = lane & 15;
  const int m0 = blockIdx.y * QBM;
  const int n0 = blockIdx.x * QBN;

  const int ca0 = t, ca1 = t + 512;
  const int ra0 = ca0 >> 2, cha0 = ca0 & 3;
  const int ra1 = ca1 >> 2, cha1 = ca1 & 3;
  const int rb = t >> 2, chb = t & 3;

  const bf16* Arow0 = A + (size_t)(m0 + ra0) * K + cha0 * 8;
  const bf16* Arow1 = A + (size_t)(m0 + ra1) * K + cha1 * 8;
  const bf16* Brow  = Bt + (size_t)(n0 + rb) * K + chb * 8;

  f32x4 acc[4][4] = {};
  const int NT = K / QBK;   // 32

  // 3 loads per tile per thread (FIFO): A,A,B
#define QKV_STAGE(KT_, B_)                                                     \
  {                                                                            \
    const int kn_ = (KT_)*QBK;                                                 \
    glds16(Arow0 + kn_, &Alds[B_][ca0 * 8]);                                   \
    glds16(Arow1 + kn_, &Alds[B_][ca1 * 8]);                                   \
    glds16(Brow + kn_, &Blds[B_][t * 8]);                                      \
  }

  QKV_STAGE(0, 0);
  QKV_STAGE(1, 1);

  for (int kt = 0; kt < NT; ++kt) {
    const int bi = kt % 3;
    if (kt + 2 < NT) {
      QKV_STAGE(kt + 2, (kt + 2) % 3);
      asm volatile("s_waitcnt vmcnt(6)" ::: "memory");   // tile kt landed
    } else if (kt + 1 < NT) {
      asm volatile("s_waitcnt vmcnt(3)" ::: "memory");
    } else {
      asm volatile("s_waitcnt vmcnt(0)" ::: "memory");
    }
    __builtin_amdgcn_s_barrier();

    bf16x8 af[4], bfr[4];
#pragma unroll
    for (int i = 0; i < 4; ++i)
      af[i] = *reinterpret_cast<const bf16x8*>(
          &Alds[bi][(wr * 64 + i * 16 + lr) * QBK + lg * 8]);
#pragma unroll
    for (int j = 0; j < 4; ++j)
      bfr[j] = *reinterpret_cast<const bf16x8*>(
          &Blds[bi][(wc * 64 + j * 16 + lr) * QBK + lg * 8]);
#pragma unroll
    for (int i = 0; i < 4; ++i)
#pragma unroll
      for (int j = 0; j < 4; ++j)
        acc[i][j] = __builtin_amdgcn_mfma_f32_16x16x32_bf16(af[i], bfr[j], acc[i][j], 0, 0, 0);

    asm volatile("s_waitcnt lgkmcnt(0)" ::: "memory");   // all reads of bi done
    __builtin_amdgcn_s_barrier();                        // before overwrite
  }

#pragma unroll
  for (int j = 0; j < 4; ++j) {
    const int n = n0 + wc * 64 + j * 16 + lr;
    const float bi = bias[n];
    const int which = n >> 10, rem = n & 1023;
    const int hh = rem >> 6, d = rem & 63;
#pragma unroll
    for (int i = 0; i < 4; ++i) {
      const int mb = m0 + wr * 64 + i * 16 + lg * 4;
      const int bb = mb >> 11, ss = mb & 2047;
      if (which == 2) {
        bf16x4 pv;
#pragma unroll
        for (int r = 0; r < 4; ++r) pv[r] = (bf16)(acc[i][j][r] + bi);
        *reinterpret_cast<bf16x4*>(
            outVt + (((size_t)bb * NH + hh) * HD + d) * SEQ + ss) = pv;
      } else if (which == 0) {
        bf16* dst = outQ + (((size_t)bb * NH + hh) * SEQ + ss) * HD + d;
#pragma unroll
        for (int r = 0; r < 4; ++r)
          dst[(size_t)r * HD] = (bf16)((acc[i][j][r] + bi) * SCALE2);
      } else {
        bf16* dst = outK + (((size_t)bb * NH + hh) * SEQ + ss) * HD + d;
#pragma unroll
        for (int r = 0; r < 4; ++r) dst[(size_t)r * HD] = (bf16)(acc[i][j][r] + bi);
      }
    }
  }
}

// ---------------- proj GEMM: 128x128 tile, BK=32, 3-buffer depth-2 pipeline --------
#define BM 128
#define BN 128
#define BK 32

__global__ __launch_bounds__(256) void gemm_proj(
    const bf16* __restrict__ A, const bf16* __restrict__ Bt,
    const float* __restrict__ bias, int M, int N, int K,
    float* __restrict__ outF) {
  __shared__ bf16 Alds[3][BM * BK];   // 3 x 8 KB
  __shared__ bf16 Blds[3][BM * BK];   // 3 x 8 KB

  const int t = threadIdx.x;
  const int lane = t & 63;
  const int w = t >> 6;
  const int wr = w >> 1, wc = w & 1;
  const int lg = lane >> 4, lr = lane & 15;
  const int m0 = blockIdx.y * BM;
  const int n0 = blockIdx.x * BN;

  const int c0 = w * 64 + lane;
  const int c1 = 256 + w * 64 + lane;
  const int r0 = c0 >> 2, ch0 = c0 & 3;
  const int r1 = c1 >> 2, ch1 = c1 & 3;

  const bf16* Arow0 = A + (size_t)(m0 + r0) * K + ch0 * 8;
  const bf16* Arow1 = A + (size_t)(m0 + r1) * K + ch1 * 8;
  const bf16* Brow0 = Bt + (size_t)(n0 + r0) * K + ch0 * 8;
  const bf16* Brow1 = Bt + (size_t)(n0 + r1) * K + ch1 * 8;

  f32x4 acc[4][4] = {};
  const int NT = K / BK;   // 32

  // 4 loads per tile per thread (FIFO): A,A,B,B
#define PRJ_STAGE(KT_, B_)                                                     \
  {                                                                            \
    const int kn_ = (KT_)*BK;                                                  \
    glds16(Arow0 + kn_, &Alds[B_][c0 * 8]);                                    \
    glds16(Arow1 + kn_, &Alds[B_][c1 * 8]);                                    \
    glds16(Brow0 + kn_, &Blds[B_][c0 * 8]);                                    \
    glds16(Brow1 + kn_, &Blds[B_][c1 * 8]);                                    \
  }

  PRJ_STAGE(0, 0);
  PRJ_STAGE(1, 1);

  for (int kt = 0; kt < NT; ++kt) {
    const int bi = kt % 3;
    if (kt + 2 < NT) {
      PRJ_STAGE(kt + 2, (kt + 2) % 3);
      asm volatile("s_waitcnt vmcnt(8)" ::: "memory");
    } else if (kt + 1 < NT) {
      asm volatile("s_waitcnt vmcnt(4)" ::: "memory");
    } else {
      asm volatile("s_waitcnt vmcnt(0)" ::: "memory");
    }
    __builtin_amdgcn_s_barrier();

    bf16x8 af[4], bfr[4];
#pragma unroll
    for (int i = 0; i < 4; ++i)
      af[i] = *reinterpret_cast<const bf16x8*>(
          &Alds[bi][(wr * 64 + i * 16 + lr) * BK + lg * 8]);
#pragma unroll
    for (int j = 0; j < 4; ++j)
      bfr[j] = *reinterpret_cast<const bf16x8*>(
          &Blds[bi][(wc * 64 + j * 16 + lr) * BK + lg * 8]);
#pragma unroll
    for (int i = 0; i < 4; ++i)
#pragma unroll
      for (int j = 0; j < 4; ++j)
        acc[i][j] = __builtin_amdgcn_mfma_f32_16x16x32_bf16(af[i], bfr[j], acc[i][j], 0, 0, 0);

    asm volatile("s_waitcnt lgkmcnt(0)" ::: "memory");
    __builtin_amdgcn_s_barrier();
  }

#pragma unroll
  for (int j = 0; j < 4; ++j) {
    const int n = n0 + wc * 64 + j * 16 + lr;
    const float bi = bias[n];
#pragma unroll
    for (int i = 0; i < 4; ++i) {
      const int mb = m0 + wr * 64 + i * 16 + lg * 4;
#pragma unroll
      for (int r = 0; r < 4; ++r)
        outF[(size_t)(mb + r) * N + n] = acc[i][j][r] + bi;
    }
  }
}

// ---------------- flash attention: 4-wave blocks (128 q-rows), K-tile = 128 ----------
// R12-exact (best measured 43.1 us): LDS-shared dbuf K/V 64 KB, balanced pairing,
// diag skip, no-max softmax P=exp2(s), lsum via ones-MFMA, counted vmcnt.
#define STAGE(kt_, buf_)                                                       \
  {                                                                            \
    const int kb_ = (kt_) << 7;                                                \
    _Pragma("unroll")                                                          \
    for (int j = 0; j < 4; ++j) {                                              \
      const int g = j * 256 + t;                                               \
      const int rowK = g >> 3, ccK = g & 7;                                    \
      const int pcK = ((ccK ^ (rowK & 7)) << 3);                               \
      glds16(Kb + headoff + (size_t)(kb_ + rowK) * HD + pcK, &Kl[buf_][g * 8]);\
      const int rowV = g >> 4, ccV = g & 15;                                   \
      const int pcV = ((ccV ^ (rowV & 15)) << 3);                              \
      glds16(Vt + headoff + (size_t)rowV * SEQ + kb_ + pcV, &Vl[buf_][g * 8]); \
    }                                                                          \
  }

#define QK_ACC(SX, X)                                                          \
  if (!diag || (X) <= w) {                                                     \
    _Pragma("unroll")                                                          \
    for (int dd = 0; dd < 4; ++dd) {                                           \
      const int pcK = (((dd * 2 + hi) ^ swzK) << 3);                           \
      bf16x8 kf = *reinterpret_cast<const bf16x8*>(                            \
          &Kl[cur][((X) * 32 + l31) * 64 + pcK]);                              \
      SX = __builtin_amdgcn_mfma_f32_32x32x16_bf16(kf, qf[dd], SX, 0, 0, 0);   \
    }                                                                          \
  }

__global__ __launch_bounds__(256, 2) void attn_fwd(
    const bf16* __restrict__ Qb, const bf16* __restrict__ Kb,
    const bf16* __restrict__ Vt, bf16* __restrict__ Ob) {
  __shared__ bf16 Kl[2][128 * 64];
  __shared__ bf16 Vl[2][64 * 128];

  const int t = threadIdx.x;
  const int lane = t & 63;
  const int w = t >> 6;           // 0..3
  const int l31 = lane & 31;
  const int hi = lane >> 5;
  const int hi8 = hi << 3;
  const int swzK = l31 & 7;
  const int swzV = l31 & 15;

  // balanced pairing: ids 0..255 -> qb 15..8, 256..511 -> qb 0..7
  const int id = blockIdx.x;
  const int qb = (id < 256) ? (15 - (id >> 5)) : ((id - 256) >> 5);
  const int bh = id & 31;
  const int h = bh & 15, b = bh >> 4;
  const size_t headoff = ((size_t)b * NH + h) * SEQ * HD;
  const int qrow = qb * 128 + w * 32 + l31;

  bf16x8 qf[4];
  {
    const bf16* qr = Qb + headoff + (size_t)qrow * HD + hi8;
#pragma unroll
    for (int d = 0; d < 4; ++d) qf[d] = *reinterpret_cast<const bf16x8*>(qr + d * 16);
  }

  bf16x8 ones;
#pragma unroll
  for (int i = 0; i < 8; ++i) ones[i] = (bf16)1.0f;

  f32x16 accO0 = {}, accO1 = {};        // O^T: d 0..31 / 32..63, col q = l31
  f32x16 accL = {};                     // row sums
  const int nkt = qb + 1;

  STAGE(0, 0);

  for (int kt = 0; kt < nkt; ++kt) {
    const int cur = kt & 1;
    if (kt + 1 < nkt) {
      STAGE(kt + 1, cur ^ 1);
      asm volatile("s_waitcnt vmcnt(8)" ::: "memory");
    } else {
      asm volatile("s_waitcnt vmcnt(0)" ::: "memory");
    }
    __builtin_amdgcn_s_barrier();

    const bool diag = (kt == nkt - 1);
    f32x16 s0 = {}, s1 = {}, s2 = {}, s3 = {};
    __builtin_amdgcn_s_setprio(1);
    QK_ACC(s0, 0)
    QK_ACC(s1, 1)
    QK_ACC(s2, 2)
    QK_ACC(s3, 3)
    __builtin_amdgcn_s_setprio(0);
    if (diag) {
      const int kq = (kt << 7) + hi * 4 - qrow;
#pragma unroll
      for (int r = 0; r < 16; ++r) {
        const int off = (r & 3) + 8 * (r >> 2);
        if (kq + off > 0) s0[r] = -1e30f;
        if (kq + off + 32 > 0) s1[r] = -1e30f;
        if (kq + off + 64 > 0) s2[r] = -1e30f;
        if (kq + off + 96 > 0) s3[r] = -1e30f;
      }
    }
#pragma unroll
    for (int r = 0; r < 16; ++r) {
      s0[r] = __builtin_amdgcn_exp2f(s0[r]);
      s1[r] = __builtin_amdgcn_exp2f(s1[r]);
      s2[r] = __builtin_amdgcn_exp2f(s2[r]);
      s3[r] = __builtin_amdgcn_exp2f(s3[r]);
    }
    uint wv[32];
    wv[0]  = cvtpk(s0[0],  s0[1]);  wv[1]  = cvtpk(s0[2],  s0[3]);
    wv[2]  = cvtpk(s0[4],  s0[5]);  wv[3]  = cvtpk(s0[6],  s0[7]);
    wv[4]  = cvtpk(s0[8],  s0[9]);  wv[5]  = cvtpk(s0[10], s0[11]);
    wv[6]  = cvtpk(s0[12], s0[13]); wv[7]  = cvtpk(s0[14], s0[15]);
    wv[8]  = cvtpk(s1[0],  s1[1]);  wv[9]  = cvtpk(s1[2],  s1[3]);
    wv[10] = cvtpk(s1[4],  s1[5]);  wv[11] = cvtpk(s1[6],  s1[7]);
    wv[12] = cvtpk(s1[8],  s1[9]);  wv[13] = cvtpk(s1[10], s1[11]);
    wv[14] = cvtpk(s1[12], s1[13]); wv[15] = cvtpk(s1[14], s1[15]);
    wv[16] = cvtpk(s2[0],  s2[1]);  wv[17] = cvtpk(s2[2],  s2[3]);
    wv[18] = cvtpk(s2[4],  s2[5]);  wv[19] = cvtpk(s2[6],  s2[7]);
    wv[20] = cvtpk(s2[8],  s2[9]);  wv[21] = cvtpk(s2[10], s2[11]);
    wv[22] = cvtpk(s2[12], s2[13]); wv[23] = cvtpk(s2[14], s2[15]);
    wv[24] = cvtpk(s3[0],  s3[1]);  wv[25] = cvtpk(s3[2],  s3[3]);
    wv[26] = cvtpk(s3[4],  s3[5]);  wv[27] = cvtpk(s3[6],  s3[7]);
    wv[28] = cvtpk(s3[8],  s3[9]);  wv[29] = cvtpk(s3[10], s3[11]);
    wv[30] = cvtpk(s3[12], s3[13]); wv[31] = cvtpk(s3[14], s3[15]);
    plswap(wv[0], wv[2]);   plswap(wv[1], wv[3]);
    plswap(wv[4], wv[6]);   plswap(wv[5], wv[7]);
    plswap(wv[8], wv[10]);  plswap(wv[9], wv[11]);
    plswap(wv[12], wv[14]); plswap(wv[13], wv[15]);
    plswap(wv[16], wv[18]); plswap(wv[17], wv[19]);
    plswap(wv[20], wv[22]); plswap(wv[21], wv[23]);
    plswap(wv[24], wv[26]); plswap(wv[25], wv[27]);
    plswap(wv[28], wv[30]); plswap(wv[29], wv[31]);
    __builtin_amdgcn_s_setprio(1);
#pragma unroll
    for (int ks = 0; ks < 8; ++ks) {
      if (!diag || ks < 2 * w + 2) {
        uint4 u = make_uint4(wv[(ks >> 1) * 8 + (ks & 1) * 4],
                             wv[(ks >> 1) * 8 + (ks & 1) * 4 + 1],
                             wv[(ks >> 1) * 8 + (ks & 1) * 4 + 2],
                             wv[(ks >> 1) * 8 + (ks & 1) * 4 + 3]);
        bf16x8 pf = *reinterpret_cast<bf16x8*>(&u);
        const int pcV = (((ks * 2 + hi) ^ swzV) << 3);
        bf16x8 vf0 = *reinterpret_cast<const bf16x8*>(&Vl[cur][l31 * 128 + pcV]);
        bf16x8 vf1 = *reinterpret_cast<const bf16x8*>(&Vl[cur][(l31 + 32) * 128 + pcV]);
        accO0 = __builtin_amdgcn_mfma_f32_32x32x16_bf16(vf0, pf, accO0, 0, 0, 0);
        accO1 = __builtin_amdgcn_mfma_f32_32x32x16_bf16(vf1, pf, accO1, 0, 0, 0);
        accL  = __builtin_amdgcn_mfma_f32_32x32x16_bf16(ones, pf, accL, 0, 0, 0);
      }
    }
    __builtin_amdgcn_s_setprio(0);
    asm volatile("s_waitcnt lgkmcnt(0)" ::: "memory");
    __builtin_amdgcn_s_barrier();
  }

  const float inv = 1.0f / accL[0];
  bf16* orow = Ob + ((size_t)b * SEQ + qrow) * EMB + h * HD + hi * 4;
#pragma unroll
  for (int rq = 0; rq < 4; ++rq) {
    bf16x4 o0, o1;
#pragma unroll
    for (int i = 0; i < 4; ++i) {
      o0[i] = (bf16)(accO0[rq * 4 + i] * inv);
      o1[i] = (bf16)(accO1[rq * 4 + i] * inv);
    }
    *reinterpret_cast<bf16x4*>(orow + rq * 8) = o0;
    *reinterpret_cast<bf16x4*>(orow + 32 + rq * 8) = o1;
  }
}

// ---------------- launch ----------------
extern "C" void kernel_launch(void* const* d_in, const int* in_sizes, int n_in,
                              void* d_out, int out_size, void* d_ws, size_t ws_size,
                              hipStream_t stream) {
  const float* x    = (const float*)d_in[0];
  const float* Wqkv = (const float*)d_in[1];
  const float* bqkv = (const float*)d_in[2];
  const float* Wout = (const float*)d_in[3];
  const float* bout = (const float*)d_in[4];
  float* out = (float*)d_out;

  char* ws = (char*)d_ws;
  bf16* xb     = (bf16*)(ws);                      // 4096x1024   8 MiB
  bf16* wqkvt  = (bf16*)(ws + 8388608);            // 3072x1024   6 MiB (W_qkv^T)
  bf16* woutt  = (bf16*)(ws + 14680064);           // 1024x1024   2 MiB (W_out^T)
  bf16* Qb     = (bf16*)(ws + 16777216);           // [b][h][s][d] 8 MiB (pre-scaled)
  bf16* Kb     = (bf16*)(ws + 25165824);           // [b][h][s][d] 8 MiB
  bf16* Vtb    = (bf16*)(ws + 33554432);           // [b][h][d][s] 8 MiB
  bf16* attnb  = (bf16*)(ws + 41943040);           // 4096x1024   8 MiB

  prep_fused<<<8192, 256, 0, stream>>>(x, xb, Wqkv, wqkvt, Wout, woutt);

  dim3 g1(3072 / QBN, 4096 / QBM);   // 24 x 16
  gemm_qkv<<<g1, 512, 0, stream>>>(xb, wqkvt, bqkv, 4096, 3072, 1024,
                                   Qb, Kb, Vtb);

  attn_fwd<<<512, 256, 0, stream>>>(Qb, Kb, Vtb, attnb);

  dim3 g2(1024 / BN, 4096 / BM);   // 8 x 32
  gemm_proj<<<g2, 256, 0, stream>>>(attnb, woutt, bout, 4096, 1024, 1024, out);
}

// Round 18
// 112.321 us; speedup vs baseline: 1.0177x; 1.0177x over previous
//
#include <hip/hip_runtime.h>
#include <hip/hip_bf16.h>
#include <math.h>

typedef __bf16 bf16;
typedef bf16 bf16x4 __attribute__((ext_vector_type(4)));
typedef bf16 bf16x8 __attribute__((ext_vector_type(8)));
typedef float f32x4 __attribute__((ext_vector_type(4)));
typedef float f32x16 __attribute__((ext_vector_type(16)));
typedef unsigned int uint;

#define EMB 1024
#define SEQ 2048
#define BATCH 2
#define NH 16
#define HD 64

#define SCALE2 0.18033688011112042f   // (1/8) * log2(e), folded into Q

// async global->LDS, 16B per lane (dest = wave-uniform base + lane*16)
__device__ __forceinline__ void glds16(const void* g, void* l) {
  __builtin_amdgcn_global_load_lds(
      (__attribute__((address_space(1))) void*)g,
      (__attribute__((address_space(3))) void*)l, 16, 0, 0);
}

// pack two f32 -> packed bf16 pair (lo=src0, hi=src1)
__device__ __forceinline__ uint cvtpk(float lo, float hi) {
  uint r;
  asm("v_cvt_pk_bf16_f32 %0, %1, %2" : "=v"(r) : "v"(lo), "v"(hi));
  return r;
}
// v_permlane32_swap_b32: a <- [a.row0, b.row0], b <- [a.row1, b.row1]
__device__ __forceinline__ void plswap(uint& a, uint& b) {
  asm("v_permlane32_swap_b32 %0, %1" : "+v"(a), "+v"(b));
}

// ---------------- fused prep: x cvt + W_qkv^T + W_out^T in ONE dispatch ----------------
// blocks [0,4096): cvt x (4096x1024 f32 -> bf16, 4 elems/thread)
// blocks [4096,7168): transpose_cvt W_qkv (1024x3072 -> 3072x1024 bf16)
// blocks [7168,8192): transpose_cvt W_out (1024x1024 -> 1024x1024 bf16)
__global__ __launch_bounds__(256) void prep_fused(
    const float* __restrict__ x, bf16* __restrict__ xb,
    const float* __restrict__ Wqkv, bf16* __restrict__ wqkvt,
    const float* __restrict__ Wout, bf16* __restrict__ woutt) {
  __shared__ float tile[32][33];
  const int blk = blockIdx.x;
  const int t = threadIdx.x;

  if (blk < 4096) {
    const int i = (blk * 256 + t) * 4;
    float4 v = *reinterpret_cast<const float4*>(x + i);
    xb[i + 0] = (bf16)v.x;
    xb[i + 1] = (bf16)v.y;
    xb[i + 2] = (bf16)v.z;
    xb[i + 3] = (bf16)v.w;
    return;
  }

  const float* in;
  bf16* out;
  int R, C, bx, by;
  if (blk < 7168) {
    const int bb = blk - 4096;           // grid (96, 32)
    in = Wqkv; out = wqkvt; R = 1024; C = 3072;
    bx = bb % 96; by = bb / 96;
  } else {
    const int bb = blk - 7168;           // grid (32, 32)
    in = Wout; out = woutt; R = 1024; C = 1024;
    bx = bb & 31; by = bb >> 5;
  }
  const int c0 = bx * 32, r0 = by * 32;
  const int tx = t & 31, ty = t >> 5;    // 32 x 8
#pragma unroll
  for (int i = 0; i < 32; i += 8)
    tile[ty + i][tx] = in[(size_t)(r0 + ty + i) * C + c0 + tx];
  __syncthreads();
#pragma unroll
  for (int i = 0; i < 32; i += 8)
    out[(size_t)(c0 + ty + i) * R + r0 + tx] = (bf16)tile[tx][ty + i];
}

// ---------------- QKV GEMM: 256x128 tile, 8 waves, BK=32, 2-phase + counted vmcnt ----
#define QBM 256
#define QBN 128
#define QBK 32

__global__ __launch_bounds__(512) void gemm_qkv(
    const bf16* __restrict__ A, const bf16* __restrict__ Bt,
    const float* __restrict__ bias, int M, int N, int K,
    bf16* __restrict__ outQ, bf16* __restrict__ outK, bf16* __restrict__ outVt) {
  __shared__ bf16 Alds[2][QBM * QBK];
  __shared__ bf16 Blds[2][QBN * QBK];

  const int t = threadIdx.x;
  const int lane = t & 63;
  const int w = t >> 6;
  const int wr = w >> 1, wc = w & 1;
  const int lg = lane >> 4, lr = lane & 15;
  const int m0 = blockIdx.y * QBM;
  const int n0 = blockIdx.x * QBN;

  const int ca0 = t, ca1 = t + 512;
  const int ra0 = ca0 >> 2, cha0 = ca0 & 3;
  const int ra1 = ca1 >> 2, cha1 = ca1 & 3;
  const int rb = t >> 2, chb = t & 3;

  const bf16* Arow0 = A + (size_t)(m0 + ra0) * K + cha0 * 8;
  const bf16* Arow1 = A + (size_t)(m0 + ra1) * K + cha1 * 8;
  const bf16* Brow  = Bt + (size_t)(n0 + rb) * K + chb * 8;

  f32x4 acc[4][4] = {};

  glds16(Arow0, &Alds[0][ca0 * 8]);
  glds16(Arow1, &Alds[0][ca1 * 8]);
  glds16(Brow, &Blds[0][t * 8]);

  int cur = 0;
  for (int k0 = 0; k0 < K; k0 += QBK) {
    if (k0 + QBK < K) {
      const int kn = k0 + QBK;
      const int nb = cur ^ 1;
      glds16(Arow0 + kn, &Alds[nb][ca0 * 8]);
      glds16(Arow1 + kn, &Alds[nb][ca1 * 8]);
      glds16(Brow + kn, &Blds[nb][t * 8]);
      asm volatile("s_waitcnt vmcnt(3)" ::: "memory");
    } else {
      asm volatile("s_waitcnt vmcnt(0)" ::: "memory");
    }
    __builtin_amdgcn_s_barrier();

    bf16x8 af[4], bfr[4];
#pragma unroll
    for (int i = 0; i < 4; ++i)
      af[i] = *reinterpret_cast<const bf16x8*>(
          &Alds[cur][(wr * 64 + i * 16 + lr) * QBK + lg * 8]);
#pragma unroll
    for (int j = 0; j < 4; ++j)
      bfr[j] = *reinterpret_cast<const bf16x8*>(
          &Blds[cur][(wc * 64 + j * 16 + lr) * QBK + lg * 8]);
#pragma unroll
    for (int i = 0; i < 4; ++i)
#pragma unroll
      for (int j = 0; j < 4; ++j)
        acc[i][j] = __builtin_amdgcn_mfma_f32_16x16x32_bf16(af[i], bfr[j], acc[i][j], 0, 0, 0);

    asm volatile("s_waitcnt lgkmcnt(0)" ::: "memory");
    __builtin_amdgcn_s_barrier();
    cur ^= 1;
  }

#pragma unroll
  for (int j = 0; j < 4; ++j) {
    const int n = n0 + wc * 64 + j * 16 + lr;
    const float bi = bias[n];
    const int which = n >> 10, rem = n & 1023;
    const int hh = rem >> 6, d = rem & 63;
#pragma unroll
    for (int i = 0; i < 4; ++i) {
      const int mb = m0 + wr * 64 + i * 16 + lg * 4;
      const int bb = mb >> 11, ss = mb & 2047;
      if (which == 2) {
        bf16x4 pv;
#pragma unroll
        for (int r = 0; r < 4; ++r) pv[r] = (bf16)(acc[i][j][r] + bi);
        *reinterpret_cast<bf16x4*>(
            outVt + (((size_t)bb * NH + hh) * HD + d) * SEQ + ss) = pv;
      } else if (which == 0) {
        bf16* dst = outQ + (((size_t)bb * NH + hh) * SEQ + ss) * HD + d;
#pragma unroll
        for (int r = 0; r < 4; ++r)
          dst[(size_t)r * HD] = (bf16)((acc[i][j][r] + bi) * SCALE2);
      } else {
        bf16* dst = outK + (((size_t)bb * NH + hh) * SEQ + ss) * HD + d;
#pragma unroll
        for (int r = 0; r < 4; ++r) dst[(size_t)r * HD] = (bf16)(acc[i][j][r] + bi);
      }
    }
  }
}

// ---------------- proj GEMM: 128x128 tile, BK=32, 2-phase + counted vmcnt ----------
#define BM 128
#define BN 128
#define BK 32

__global__ __launch_bounds__(256) void gemm_proj(
    const bf16* __restrict__ A, const bf16* __restrict__ Bt,
    const float* __restrict__ bias, int M, int N, int K,
    float* __restrict__ outF) {
  __shared__ bf16 Alds[2][BM * BK];
  __shared__ bf16 Blds[2][BM * BK];

  const int t = threadIdx.x;
  const int lane = t & 63;
  const int w = t >> 6;
  const int wr = w >> 1, wc = w & 1;
  const int lg = lane >> 4, lr = lane & 15;
  const int m0 = blockIdx.y * BM;
  const int n0 = blockIdx.x * BN;

  const int c0 = w * 64 + lane;
  const int c1 = 256 + w * 64 + lane;
  const int r0 = c0 >> 2, ch0 = c0 & 3;
  const int r1 = c1 >> 2, ch1 = c1 & 3;

  const bf16* Arow0 = A + (size_t)(m0 + r0) * K + ch0 * 8;
  const bf16* Arow1 = A + (size_t)(m0 + r1) * K + ch1 * 8;
  const bf16* Brow0 = Bt + (size_t)(n0 + r0) * K + ch0 * 8;
  const bf16* Brow1 = Bt + (size_t)(n0 + r1) * K + ch1 * 8;

  f32x4 acc[4][4] = {};

  glds16(Arow0, &Alds[0][c0 * 8]);
  glds16(Arow1, &Alds[0][c1 * 8]);
  glds16(Brow0, &Blds[0][c0 * 8]);
  glds16(Brow1, &Blds[0][c1 * 8]);

  int cur = 0;
  for (int k0 = 0; k0 < K; k0 += BK) {
    if (k0 + BK < K) {
      const int kn = k0 + BK;
      const int nb = cur ^ 1;
      glds16(Arow0 + kn, &Alds[nb][c0 * 8]);
      glds16(Arow1 + kn, &Alds[nb][c1 * 8]);
      glds16(Brow0 + kn, &Blds[nb][c0 * 8]);
      glds16(Brow1 + kn, &Blds[nb][c1 * 8]);
      asm volatile("s_waitcnt vmcnt(4)" ::: "memory");
    } else {
      asm volatile("s_waitcnt vmcnt(0)" ::: "memory");
    }
    __builtin_amdgcn_s_barrier();

    bf16x8 af[4], bfr[4];
#pragma unroll
    for (int i = 0; i < 4; ++i)
      af[i] = *reinterpret_cast<const bf16x8*>(
          &Alds[cur][(wr * 64 + i * 16 + lr) * BK + lg * 8]);
#pragma unroll
    for (int j = 0; j < 4; ++j)
      bfr[j] = *reinterpret_cast<const bf16x8*>(
          &Blds[cur][(wc * 64 + j * 16 + lr) * BK + lg * 8]);
#pragma unroll
    for (int i = 0; i < 4; ++i)
#pragma unroll
      for (int j = 0; j < 4; ++j)
        acc[i][j] = __builtin_amdgcn_mfma_f32_16x16x32_bf16(af[i], bfr[j], acc[i][j], 0, 0, 0);

    asm volatile("s_waitcnt lgkmcnt(0)" ::: "memory");
    __builtin_amdgcn_s_barrier();
    cur ^= 1;
  }

#pragma unroll
  for (int j = 0; j < 4; ++j) {
    const int n = n0 + wc * 64 + j * 16 + lr;
    const float bi = bias[n];
#pragma unroll
    for (int i = 0; i < 4; ++i) {
      const int mb = m0 + wr * 64 + i * 16 + lg * 4;
#pragma unroll
      for (int r = 0; r < 4; ++r)
        outF[(size_t)(mb + r) * N + n] = acc[i][j][r] + bi;
    }
  }
}

// ---------------- flash attention: 4-wave blocks (128 q-rows), K-tile = 128 ----------
// R12-exact (best measured 43.1 us): LDS-shared dbuf K/V 64 KB, balanced pairing,
// diag skip, no-max softmax P=exp2(s), lsum via ones-MFMA, counted vmcnt.
#define STAGE(kt_, buf_)                                                       \
  {                                                                            \
    const int kb_ = (kt_) << 7;                                                \
    _Pragma("unroll")                                                          \
    for (int j = 0; j < 4; ++j) {                                              \
      const int g = j * 256 + t;                                               \
      const int rowK = g >> 3, ccK = g & 7;                                    \
      const int pcK = ((ccK ^ (rowK & 7)) << 3);                               \
      glds16(Kb + headoff + (size_t)(kb_ + rowK) * HD + pcK, &Kl[buf_][g * 8]);\
      const int rowV = g >> 4, ccV = g & 15;                                   \
      const int pcV = ((ccV ^ (rowV & 15)) << 3);                              \
      glds16(Vt + headoff + (size_t)rowV * SEQ + kb_ + pcV, &Vl[buf_][g * 8]); \
    }                                                                          \
  }

#define QK_ACC(SX, X)                                                          \
  if (!diag || (X) <= w) {                                                     \
    _Pragma("unroll")                                                          \
    for (int dd = 0; dd < 4; ++dd) {                                           \
      const int pcK = (((dd * 2 + hi) ^ swzK) << 3);                           \
      bf16x8 kf = *reinterpret_cast<const bf16x8*>(                            \
          &Kl[cur][((X) * 32 + l31) * 64 + pcK]);                              \
      SX = __builtin_amdgcn_mfma_f32_32x32x16_bf16(kf, qf[dd], SX, 0, 0, 0);   \
    }                                                                          \
  }

__global__ __launch_bounds__(256, 2) void attn_fwd(
    const bf16* __restrict__ Qb, const bf16* __restrict__ Kb,
    const bf16* __restrict__ Vt, bf16* __restrict__ Ob) {
  __shared__ bf16 Kl[2][128 * 64];
  __shared__ bf16 Vl[2][64 * 128];

  const int t = threadIdx.x;
  const int lane = t & 63;
  const int w = t >> 6;           // 0..3
  const int l31 = lane & 31;
  const int hi = lane >> 5;
  const int hi8 = hi << 3;
  const int swzK = l31 & 7;
  const int swzV = l31 & 15;

  // balanced pairing: ids 0..255 -> qb 15..8, 256..511 -> qb 0..7
  const int id = blockIdx.x;
  const int qb = (id < 256) ? (15 - (id >> 5)) : ((id - 256) >> 5);
  const int bh = id & 31;
  const int h = bh & 15, b = bh >> 4;
  const size_t headoff = ((size_t)b * NH + h) * SEQ * HD;
  const int qrow = qb * 128 + w * 32 + l31;

  bf16x8 qf[4];
  {
    const bf16* qr = Qb + headoff + (size_t)qrow * HD + hi8;
#pragma unroll
    for (int d = 0; d < 4; ++d) qf[d] = *reinterpret_cast<const bf16x8*>(qr + d * 16);
  }

  bf16x8 ones;
#pragma unroll
  for (int i = 0; i < 8; ++i) ones[i] = (bf16)1.0f;

  f32x16 accO0 = {}, accO1 = {};        // O^T: d 0..31 / 32..63, col q = l31
  f32x16 accL = {};                     // row sums
  const int nkt = qb + 1;

  STAGE(0, 0);

  for (int kt = 0; kt < nkt; ++kt) {
    const int cur = kt & 1;
    if (kt + 1 < nkt) {
      STAGE(kt + 1, cur ^ 1);
      asm volatile("s_waitcnt vmcnt(8)" ::: "memory");
    } else {
      asm volatile("s_waitcnt vmcnt(0)" ::: "memory");
    }
    __builtin_amdgcn_s_barrier();

    const bool diag = (kt == nkt - 1);
    f32x16 s0 = {}, s1 = {}, s2 = {}, s3 = {};
    __builtin_amdgcn_s_setprio(1);
    QK_ACC(s0, 0)
    QK_ACC(s1, 1)
    QK_ACC(s2, 2)
    QK_ACC(s3, 3)
    __builtin_amdgcn_s_setprio(0);
    if (diag) {
      const int kq = (kt << 7) + hi * 4 - qrow;
#pragma unroll
      for (int r = 0; r < 16; ++r) {
        const int off = (r & 3) + 8 * (r >> 2);
        if (kq + off > 0) s0[r] = -1e30f;
        if (kq + off + 32 > 0) s1[r] = -1e30f;
        if (kq + off + 64 > 0) s2[r] = -1e30f;
        if (kq + off + 96 > 0) s3[r] = -1e30f;
      }
    }
#pragma unroll
    for (int r = 0; r < 16; ++r) {
      s0[r] = __builtin_amdgcn_exp2f(s0[r]);
      s1[r] = __builtin_amdgcn_exp2f(s1[r]);
      s2[r] = __builtin_amdgcn_exp2f(s2[r]);
      s3[r] = __builtin_amdgcn_exp2f(s3[r]);
    }
    uint wv[32];
    wv[0]  = cvtpk(s0[0],  s0[1]);  wv[1]  = cvtpk(s0[2],  s0[3]);
    wv[2]  = cvtpk(s0[4],  s0[5]);  wv[3]  = cvtpk(s0[6],  s0[7]);
    wv[4]  = cvtpk(s0[8],  s0[9]);  wv[5]  = cvtpk(s0[10], s0[11]);
    wv[6]  = cvtpk(s0[12], s0[13]); wv[7]  = cvtpk(s0[14], s0[15]);
    wv[8]  = cvtpk(s1[0],  s1[1]);  wv[9]  = cvtpk(s1[2],  s1[3]);
    wv[10] = cvtpk(s1[4],  s1[5]);  wv[11] = cvtpk(s1[6],  s1[7]);
    wv[12] = cvtpk(s1[8],  s1[9]);  wv[13] = cvtpk(s1[10], s1[11]);
    wv[14] = cvtpk(s1[12], s1[13]); wv[15] = cvtpk(s1[14], s1[15]);
    wv[16] = cvtpk(s2[0],  s2[1]);  wv[17] = cvtpk(s2[2],  s2[3]);
    wv[18] = cvtpk(s2[4],  s2[5]);  wv[19] = cvtpk(s2[6],  s2[7]);
    wv[20] = cvtpk(s2[8],  s2[9]);  wv[21] = cvtpk(s2[10], s2[11]);
    wv[22] = cvtpk(s2[12], s2[13]); wv[23] = cvtpk(s2[14], s2[15]);
    wv[24] = cvtpk(s3[0],  s3[1]);  wv[25] = cvtpk(s3[2],  s3[3]);
    wv[26] = cvtpk(s3[4],  s3[5]);  wv[27] = cvtpk(s3[6],  s3[7]);
    wv[28] = cvtpk(s3[8],  s3[9]);  wv[29] = cvtpk(s3[10], s3[11]);
    wv[30] = cvtpk(s3[12], s3[13]); wv[31] = cvtpk(s3[14], s3[15]);
    plswap(wv[0], wv[2]);   plswap(wv[1], wv[3]);
    plswap(wv[4], wv[6]);   plswap(wv[5], wv[7]);
    plswap(wv[8], wv[10]);  plswap(wv[9], wv[11]);
    plswap(wv[12], wv[14]); plswap(wv[13], wv[15]);
    plswap(wv[16], wv[18]); plswap(wv[17], wv[19]);
    plswap(wv[20], wv[22]); plswap(wv[21], wv[23]);
    plswap(wv[24], wv[26]); plswap(wv[25], wv[27]);
    plswap(wv[28], wv[30]); plswap(wv[29], wv[31]);
    __builtin_amdgcn_s_setprio(1);
#pragma unroll
    for (int ks = 0; ks < 8; ++ks) {
      if (!diag || ks < 2 * w + 2) {
        uint4 u = make_uint4(wv[(ks >> 1) * 8 + (ks & 1) * 4],
                             wv[(ks >> 1) * 8 + (ks & 1) * 4 + 1],
                             wv[(ks >> 1) * 8 + (ks & 1) * 4 + 2],
                             wv[(ks >> 1) * 8 + (ks & 1) * 4 + 3]);
        bf16x8 pf = *reinterpret_cast<bf16x8*>(&u);
        const int pcV = (((ks * 2 + hi) ^ swzV) << 3);
        bf16x8 vf0 = *reinterpret_cast<const bf16x8*>(&Vl[cur][l31 * 128 + pcV]);
        bf16x8 vf1 = *reinterpret_cast<const bf16x8*>(&Vl[cur][(l31 + 32) * 128 + pcV]);
        accO0 = __builtin_amdgcn_mfma_f32_32x32x16_bf16(vf0, pf, accO0, 0, 0, 0);
        accO1 = __builtin_amdgcn_mfma_f32_32x32x16_bf16(vf1, pf, accO1, 0, 0, 0);
        accL  = __builtin_amdgcn_mfma_f32_32x32x16_bf16(ones, pf, accL, 0, 0, 0);
      }
    }
    __builtin_amdgcn_s_setprio(0);
    asm volatile("s_waitcnt lgkmcnt(0)" ::: "memory");
    __builtin_amdgcn_s_barrier();
  }

  const float inv = 1.0f / accL[0];
  bf16* orow = Ob + ((size_t)b * SEQ + qrow) * EMB + h * HD + hi * 4;
#pragma unroll
  for (int rq = 0; rq < 4; ++rq) {
    bf16x4 o0, o1;
#pragma unroll
    for (int i = 0; i < 4; ++i) {
      o0[i] = (bf16)(accO0[rq * 4 + i] * inv);
      o1[i] = (bf16)(accO1[rq * 4 + i] * inv);
    }
    *reinterpret_cast<bf16x4*>(orow + rq * 8) = o0;
    *reinterpret_cast<bf16x4*>(orow + 32 + rq * 8) = o1;
  }
}

// ---------------- launch ----------------
extern "C" void kernel_launch(void* const* d_in, const int* in_sizes, int n_in,
                              void* d_out, int out_size, void* d_ws, size_t ws_size,
                              hipStream_t stream) {
  const float* x    = (const float*)d_in[0];
  const float* Wqkv = (const float*)d_in[1];
  const float* bqkv = (const float*)d_in[2];
  const float* Wout = (const float*)d_in[3];
  const float* bout = (const float*)d_in[4];
  float* out = (float*)d_out;

  char* ws = (char*)d_ws;
  bf16* xb     = (bf16*)(ws);                      // 4096x1024   8 MiB
  bf16* wqkvt  = (bf16*)(ws + 8388608);            // 3072x1024   6 MiB (W_qkv^T)
  bf16* woutt  = (bf16*)(ws + 14680064);           // 1024x1024   2 MiB (W_out^T)
  bf16* Qb     = (bf16*)(ws + 16777216);           // [b][h][s][d] 8 MiB (pre-scaled)
  bf16* Kb     = (bf16*)(ws + 25165824);           // [b][h][s][d] 8 MiB
  bf16* Vtb    = (bf16*)(ws + 33554432);           // [b][h][d][s] 8 MiB
  bf16* attnb  = (bf16*)(ws + 41943040);           // 4096x1024   8 MiB

  prep_fused<<<8192, 256, 0, stream>>>(x, xb, Wqkv, wqkvt, Wout, woutt);

  dim3 g1(3072 / QBN, 4096 / QBM);   // 24 x 16
  gemm_qkv<<<g1, 512, 0, stream>>>(xb, wqkvt, bqkv, 4096, 3072, 1024,
                                   Qb, Kb, Vtb);

  attn_fwd<<<512, 256, 0, stream>>>(Qb, Kb, Vtb, attnb);

  dim3 g2(1024 / BN, 4096 / BM);   // 8 x 32
  gemm_proj<<<g2, 256, 0, stream>>>(attnb, woutt, bout, 4096, 1024, 1024, out);
}